// Round 7
// baseline (342.263 us; speedup 1.0000x reference)
//
#include <hip/hip_runtime.h>

#define BB 32
#define NN 16384

typedef __attribute__((ext_vector_type(4))) float f4;
typedef __attribute__((ext_vector_type(8))) short short8;

__device__ __forceinline__ unsigned int f2bf(float f) {
  unsigned int u = __float_as_uint(f);
  return (u + 0x7fffu + ((u >> 16) & 1u)) >> 16;
}
__device__ __forceinline__ short bfs(float f) { return (short)f2bf(f); }

// ---------------------------------------------------------------------------
// prep: M = Wq^T @ Wk  (64x64);  Wihv = W_ih @ Wv  (192x64).
// ---------------------------------------------------------------------------
__global__ void __launch_bounds__(256) prep_kernel(
    const float* __restrict__ Wq, const float* __restrict__ Wk,
    const float* __restrict__ W_ih, const float* __restrict__ Wv,
    float* __restrict__ M, float* __restrict__ Wihv)
{
  int id = blockIdx.x * 256 + threadIdx.x;  // grid 64 -> 16384
  if (id < 4096) {
    int e1 = id >> 6, e2 = id & 63;
    float acc = 0.f;
    for (int d = 0; d < 64; ++d) acc += Wq[d * 64 + e1] * Wk[d * 64 + e2];
    M[id] = acc;
  } else {
    int t = (id - 4096) >> 6, e = id & 63;
    float acc = 0.f;
    for (int k = 0; k < 64; ++k) acc += W_ih[t * 64 + k] * Wv[k * 64 + e];
    Wihv[t * 64 + e] = acc;
  }
}

// ---------------------------------------------------------------------------
// init_qk: slots = mu + exp(lsig)*noise; qk = bf16(LN(slots) @ M * 0.125).
// ---------------------------------------------------------------------------
__global__ void __launch_bounds__(64) init_qk_kernel(
    const float* __restrict__ noise, const float* __restrict__ mu,
    const float* __restrict__ lsig, float* __restrict__ slots,
    const float* __restrict__ gs, const float* __restrict__ bsl,
    const float* __restrict__ M, unsigned short* __restrict__ qkb)
{
  const int bsi = blockIdx.x, l = threadIdx.x;
  const int idx = bsi * 64 + l;
  __shared__ float sh[64];
  float v = mu[idx & 511] + __expf(lsig[idx & 511]) * noise[idx];
  slots[idx] = v;
  float sm = v, sq = v * v;
#pragma unroll
  for (int m = 1; m < 64; m <<= 1) { sm += __shfl_xor(sm, m); sq += __shfl_xor(sq, m); }
  float mean = sm * (1.f / 64.f);
  float var = sq * (1.f / 64.f) - mean * mean;
  sh[l] = (v - mean) * rsqrtf(var + 1e-5f) * gs[l] + bsl[l];
  float acc = 0.f;
  for (int k = 0; k < 64; ++k) acc += sh[k] * M[k * 64 + l];
  qkb[idx] = (unsigned short)f2bf(acc * 0.125f);
}

// ---------------------------------------------------------------------------
// attn: MODE 0 = read x fp32, LN, write Xn bf16 + XnT bf16 (transposed copy),
//                fused iter-1 attention (PV via LDS XT tiles it builds anyway).
//       MODE 1 = read Xn (logits) + XnT (PV B-frags direct) — no LDS transpose.
// grid 1024 (= 32 b x 32 ch, 512 rows/block), 256 thr = 4 waves x 32-row units.
// Logits (transposed form): lg = mfma(qkA, a) : D[s'=quad*4+r][n=l15];
//   slot-sum = in-lane add4 + xor16 + xor32, x0.5. Pt[s'][n] <- p.
// PV: pf = Pt[l15][quad*8..] (A-frag P^T), cv[t] = B[k=n][col=e]:
//   MODE0 from LDS XT (stride 56, +((e>>3)&3)*8 shift), MODE1 from global XnT.
// XnT layout: [b][e][n]  (row stride NN shorts).
// ---------------------------------------------------------------------------
template <int MODE>
__global__ void __launch_bounds__(256) attn_kernel(
    const float* __restrict__ x, const unsigned short* __restrict__ Xin,
    const float* __restrict__ gin, const float* __restrict__ bin,
    unsigned short* __restrict__ Xout, unsigned short* __restrict__ XnT,
    const unsigned short* __restrict__ qkb,
    float* __restrict__ Wpart, float* __restrict__ cpart)
{
  constexpr int SMS = (MODE == 0) ? 16896 : 6720;
  __shared__ __align__(16) unsigned short SMEM[SMS];

  const int tid = threadIdx.x, wave = tid >> 6, lane = tid & 63;
  const int l15 = lane & 15, quad = lane >> 4;
  const int blk = blockIdx.x;
  const int b = blk >> 5;
  const int k0 = quad * 8;

  unsigned short* xt  = (MODE == 0) ? (SMEM + wave * 3584) : nullptr;
  unsigned short* Ptw = (MODE == 0) ? (SMEM + 14336 + wave * 640)
                                    : (SMEM + wave * 640);

  // qk fragments: per-lane qk[s=l15&7][e=k0+jj]; A[row=l15][k=e] (dup rows).
  const unsigned short* qrow = qkb + (((b << 3) + (l15 & 7)) << 6) + k0;
  const short8 qkA0 = *(const short8*)qrow;
  const short8 qkA1 = *(const short8*)(qrow + 32);

  f4 g0a, g0b, g1a, g1b, h0a, h0b, h1a, h1b;
  if constexpr (MODE == 0) {
    g0a = *(const f4*)(gin + k0);      g0b = *(const f4*)(gin + k0 + 4);
    g1a = *(const f4*)(gin + k0 + 32); g1b = *(const f4*)(gin + k0 + 36);
    h0a = *(const f4*)(bin + k0);      h0b = *(const f4*)(bin + k0 + 4);
    h1a = *(const f4*)(bin + k0 + 32); h1b = *(const f4*)(bin + k0 + 36);
  }

  const size_t row00 = (size_t)blk * 512 + wave * 32 + l15;  // unit0 half0 row
  const int nbase = ((blk & 31) << 9) + (wave << 5);          // n-in-batch base

  f4 wacc[4];
#pragma unroll
  for (int t = 0; t < 4; ++t) wacc[t] = (f4){0.f, 0.f, 0.f, 0.f};
  float cac0 = 0.f, cac1 = 0.f, cac2 = 0.f, cac3 = 0.f;

  f4 cc[2][4];      // MODE 0 current unit (fp32)
  short8 aa[2][2];  // MODE 1 current unit (bf16)
  short8 cv[4];     // MODE 1 current unit PV B-frags
  // MODE1 XnT per-lane base: row (b*64 + l15), col nbase + quad*8
  const unsigned short* vB =
      (MODE == 1) ? (XnT + (((size_t)((b << 6) + l15)) << 14) + nbase + (quad << 3))
                  : nullptr;

  if constexpr (MODE == 0) {
    const float* xp = x + row00 * 64 + k0;
#pragma unroll
    for (int s = 0; s < 2; ++s) {
      const float* sp = xp + s * 1024;
      cc[s][0] = *(const f4*)sp;        cc[s][1] = *(const f4*)(sp + 4);
      cc[s][2] = *(const f4*)(sp + 32); cc[s][3] = *(const f4*)(sp + 36);
    }
  } else {
    const unsigned short* xb = Xin + row00 * 64 + k0;
#pragma unroll
    for (int s = 0; s < 2; ++s) {
      aa[s][0] = *(const short8*)(xb + s * 1024);
      aa[s][1] = *(const short8*)(xb + s * 1024 + 32);
    }
#pragma unroll
    for (int t = 0; t < 4; ++t)
      cv[t] = *(const short8*)(vB + ((size_t)t << 18));
  }

#pragma unroll
  for (int u = 0; u < 4; ++u) {
    f4 nc[2][4];
    short8 na[2][2];
    short8 nv[4];
    if (u < 3) {  // prefetch next unit (128 rows ahead)
      if constexpr (MODE == 0) {
        const float* xp = x + (row00 + (size_t)(u + 1) * 128) * 64 + k0;
#pragma unroll
        for (int s = 0; s < 2; ++s) {
          const float* sp = xp + s * 1024;
          nc[s][0] = *(const f4*)sp;        nc[s][1] = *(const f4*)(sp + 4);
          nc[s][2] = *(const f4*)(sp + 32); nc[s][3] = *(const f4*)(sp + 36);
        }
      } else {
        const unsigned short* xb = Xin + (row00 + (size_t)(u + 1) * 128) * 64 + k0;
#pragma unroll
        for (int s = 0; s < 2; ++s) {
          na[s][0] = *(const short8*)(xb + s * 1024);
          na[s][1] = *(const short8*)(xb + s * 1024 + 32);
        }
#pragma unroll
        for (int t = 0; t < 4; ++t)
          nv[t] = *(const short8*)(vB + ((size_t)t << 18) + ((u + 1) << 7));
      }
    }

#pragma unroll
    for (int s = 0; s < 2; ++s) {
      short8 a0, a1;
      if constexpr (MODE == 0) {
        float sm = 0.f, sq = 0.f;
#pragma unroll
        for (int j = 0; j < 4; ++j) {
          float v0 = cc[s][0][j], v1 = cc[s][1][j], v2 = cc[s][2][j], v3 = cc[s][3][j];
          sm += v0 + v1 + v2 + v3;
          sq += v0 * v0 + v1 * v1 + v2 * v2 + v3 * v3;
        }
        sm += __shfl_xor(sm, 16); sq += __shfl_xor(sq, 16);
        sm += __shfl_xor(sm, 32); sq += __shfl_xor(sq, 32);
        const float mean = sm * (1.f / 64.f);
        const float var = sq * (1.f / 64.f) - mean * mean;
        const float rstd = rsqrtf(var + 1e-5f);
#pragma unroll
        for (int j = 0; j < 4; ++j) {
          a0[j]     = bfs((cc[s][0][j] - mean) * rstd * g0a[j] + h0a[j]);
          a0[j + 4] = bfs((cc[s][1][j] - mean) * rstd * g0b[j] + h0b[j]);
          a1[j]     = bfs((cc[s][2][j] - mean) * rstd * g1a[j] + h1a[j]);
          a1[j + 4] = bfs((cc[s][3][j] - mean) * rstd * g1b[j] + h1b[j]);
        }
        unsigned short* xo = Xout + (row00 + (size_t)u * 128 + s * 16) * 64 + k0;
        *(short8*)xo = a0;
        *(short8*)(xo + 32) = a1;
        // scalar transposed stores: XT[e][n] at e*56 + ((e>>3)&3)*8 + n.
        const int nn = s * 16 + l15;
        unsigned short* xb0 = xt + (quad << 3) + nn;
#pragma unroll
        for (int jj = 0; jj < 8; ++jj) {
          xb0[(k0 + jj) * 56]      = (unsigned short)a0[jj];
          xb0[(k0 + jj + 32) * 56] = (unsigned short)a1[jj];
        }
      } else {
        a0 = aa[s][0]; a1 = aa[s][1];
      }

      // logits (transposed form): D[s'=quad*4+r][n=l15]; rows 8..15 dup 0..7
      f4 lg = (f4){0.f, 0.f, 0.f, 0.f};
      lg = __builtin_amdgcn_mfma_f32_16x16x32_bf16(qkA0, a0, lg, 0, 0, 0);
      lg = __builtin_amdgcn_mfma_f32_16x16x32_bf16(qkA1, a1, lg, 0, 0, 0);
      const float e0 = __expf(lg[0]), e1 = __expf(lg[1]);
      const float e2 = __expf(lg[2]), e3 = __expf(lg[3]);
      float ss = e0 + e1 + e2 + e3;
      ss += __shfl_xor(ss, 16);
      ss += __shfl_xor(ss, 32);         // sum over all 16 rows = 2x real sum
      const float rs = __builtin_amdgcn_rcpf(ss * 0.5f);
      const float p0 = e0 * rs, p1 = e1 * rs, p2 = e2 * rs, p3 = e3 * rs;
      cac0 += p0; cac1 += p1; cac2 += p2; cac3 += p3;
      unsigned short* pw = Ptw + (quad << 2) * 40 + s * 16 + l15;
      pw[0]   = (unsigned short)f2bf(p0);
      pw[40]  = (unsigned short)f2bf(p1);
      pw[80]  = (unsigned short)f2bf(p2);
      pw[120] = (unsigned short)f2bf(p3);
    }

    // P^T A-frag (same-wave DS ordering, proven pattern)
    short8 pf = *(const short8*)(Ptw + l15 * 40 + quad * 8);
#pragma unroll
    for (int t = 0; t < 4; ++t) {
      short8 cvv;
      if constexpr (MODE == 0) {
        const int rr = t * 16 + l15;
        cvv = *(const short8*)(xt + rr * 56 + (((rr >> 3) & 3) << 3) + (quad << 3));
      } else {
        cvv = cv[t];
      }
      wacc[t] = __builtin_amdgcn_mfma_f32_16x16x32_bf16(pf, cvv, wacc[t], 0, 0, 0);
    }

    if constexpr (MODE == 0) {
      // dump this unit's XT tile to global XnT (coalesced 64B segments)
      const int nb = nbase + (u << 7);
#pragma unroll
      for (int pass = 0; pass < 4; ++pass) {
        const int e = (pass << 4) + (lane >> 2);
        const int no = (lane & 3) << 3;
        const short8 vv =
            *(const short8*)(xt + e * 56 + (((e >> 3) & 3) << 3) + no);
        *(short8*)(XnT + (((size_t)((b << 6) + e)) << 14) + nb + no) = vv;
      }
    }

    if (u < 3) {
      if constexpr (MODE == 0) {
#pragma unroll
        for (int s = 0; s < 2; ++s)
#pragma unroll
          for (int j = 0; j < 4; ++j) cc[s][j] = nc[s][j];
      } else {
#pragma unroll
        for (int s = 0; s < 2; ++s) { aa[s][0] = na[s][0]; aa[s][1] = na[s][1]; }
#pragma unroll
        for (int t = 0; t < 4; ++t) cv[t] = nv[t];
      }
    }
  }

  // epilogue: reduce cac over the 16 columns (n), stash per-wave partials.
#pragma unroll
  for (int m = 1; m < 16; m <<= 1) {
    cac0 += __shfl_xor(cac0, m); cac1 += __shfl_xor(cac1, m);
    cac2 += __shfl_xor(cac2, m); cac3 += __shfl_xor(cac3, m);
  }
  float* redw;
  float* credw;
  if constexpr (MODE == 0) {   // overlay each wave's own XT region
    redw  = (float*)(SMEM + wave * 3584);
    credw = (float*)(SMEM + wave * 3584 + 1024);
  } else {
    redw  = (float*)(SMEM + 2560) + wave * 512;
    credw = (float*)(SMEM + 6656) + wave * 8;
  }
  if (l15 == 0 && quad < 2) {
    credw[quad * 4 + 0] = cac0; credw[quad * 4 + 1] = cac1;
    credw[quad * 4 + 2] = cac2; credw[quad * 4 + 3] = cac3;
  }
  if (quad < 2) {  // D rows 8..15 are s-duplicates
#pragma unroll
    for (int t = 0; t < 4; ++t)
#pragma unroll
      for (int r = 0; r < 4; ++r)
        redw[(quad * 4 + r) * 64 + (t << 4) + l15] = wacc[t][r];
  }
  __syncthreads();
  for (int i = tid; i < 512; i += 256) {
    float acc = 0.f;
#pragma unroll
    for (int w = 0; w < 4; ++w) {
      const float* rw = (MODE == 0) ? (const float*)(SMEM + w * 3584)
                                    : (const float*)(SMEM + 2560) + w * 512;
      acc += rw[i];
    }
    Wpart[(size_t)blk * 512 + i] = acc;
  }
  if (tid < 8) {
    float acc = 0.f;
#pragma unroll
    for (int w = 0; w < 4; ++w) {
      const float* cw = (MODE == 0) ? (const float*)(SMEM + w * 3584 + 1024)
                                    : (const float*)(SMEM + 6656) + w * 8;
      acc += cw[tid];
    }
    cpart[blk * 8 + tid] = acc;
  }
}

// ---------------------------------------------------------------------------
// update: per (b,s). xmean -> gi via Wihv (= W_ih@Wv), GRU + LN + MLP + res;
// emits next qk (= LN(slots_new) @ M * 0.125) when make_q.
// ---------------------------------------------------------------------------
__global__ void __launch_bounds__(256) update_kernel(
    const float* __restrict__ Wpart, const float* __restrict__ cpart,
    const float* __restrict__ slots, float* __restrict__ out,
    const float* __restrict__ Wihv, const float* __restrict__ W_hh,
    const float* __restrict__ b_ih, const float* __restrict__ b_hh,
    const float* __restrict__ g_mlp, const float* __restrict__ b_mlp,
    const float* __restrict__ W1, const float* __restrict__ b1,
    const float* __restrict__ W2, const float* __restrict__ b2,
    const float* __restrict__ gs, const float* __restrict__ bsl,
    const float* __restrict__ M, unsigned short* __restrict__ qkb, int make_q)
{
  const int bs = blockIdx.x;
  const int b = bs >> 3, s = bs & 7;
  const int tid = threadIdx.x;
  const int l = tid & 63, cq = tid >> 6;
  __shared__ float wred[4][64];
  __shared__ float credS[4];
  __shared__ float u_sh[64], sp_sh[64], giA[192], ghA[192], uln_sh[64], h_sh[128];

  float wp = 0.f, cp2 = 0.f;
  for (int c = cq * 8; c < cq * 8 + 8; ++c) {
    wp += Wpart[(size_t)(((b << 5) + c) * 8 + s) * 64 + l];
    cp2 += cpart[((b << 5) + c) * 8 + s];
  }
  wred[cq][l] = wp;
  if (l == 0) credS[cq] = cp2;
  __syncthreads();

  float sp = 0.f;
  if (tid < 64) {
    const float cs = credS[0] + credS[1] + credS[2] + credS[3];
    const float u = (wred[0][l] + wred[1][l] + wred[2][l] + wred[3][l]) / cs;
    sp = slots[(b * 8 + s) * 64 + l];
    u_sh[l] = u; sp_sh[l] = sp;   // u_sh holds xmean (pre-Wv space)
  }
  __syncthreads();

  if (tid < 192) {
    float accI = b_ih[tid], accH = b_hh[tid];
    const float* wi = Wihv + tid * 64;
    const float* wh = W_hh + tid * 64;
    for (int k = 0; k < 64; ++k) { accI += u_sh[k] * wi[k]; accH += sp_sh[k] * wh[k]; }
    giA[tid] = accI; ghA[tid] = accH;
  }
  __syncthreads();

  float upd = 0.f;
  if (tid < 64) {
    const float rg = 1.f / (1.f + __expf(-(giA[l] + ghA[l])));
    const float zg = 1.f / (1.f + __expf(-(giA[64 + l] + ghA[64 + l])));
    const float ng = tanhf(giA[128 + l] + rg * ghA[128 + l]);
    upd = (1.f - zg) * ng + zg * sp;
    float sm = upd, sq = upd * upd;
#pragma unroll
    for (int m = 1; m < 64; m <<= 1) { sm += __shfl_xor(sm, m); sq += __shfl_xor(sq, m); }
    const float mean = sm * (1.f / 64.f);
    const float var = sq * (1.f / 64.f) - mean * mean;
    uln_sh[l] = (upd - mean) * rsqrtf(var + 1e-5f) * g_mlp[l] + b_mlp[l];
  }
  __syncthreads();

  if (tid < 128) {
    float acc = b1[tid];
    const float* w1 = W1 + tid * 64;
    for (int k = 0; k < 64; ++k) acc += uln_sh[k] * w1[k];
    h_sh[tid] = fmaxf(acc, 0.f);
  }
  __syncthreads();

  if (tid < 64) {
    float acc = b2[l];
    const float* w2 = W2 + l * 128;
    for (int k = 0; k < 128; ++k) acc += h_sh[k] * w2[k];
    const float sv = upd + acc;
    out[(b * 8 + s) * 64 + l] = sv;
    if (make_q) {
      float sm2 = sv, sq2 = sv * sv;
#pragma unroll
      for (int m = 1; m < 64; m <<= 1) { sm2 += __shfl_xor(sm2, m); sq2 += __shfl_xor(sq2, m); }
      const float mean2 = sm2 * (1.f / 64.f);
      const float var2 = sq2 * (1.f / 64.f) - mean2 * mean2;
      u_sh[l] = (sv - mean2) * rsqrtf(var2 + 1e-5f) * gs[l] + bsl[l];
      float qa = 0.f;
      for (int k = 0; k < 64; ++k) qa += u_sh[k] * M[k * 64 + l];
      qkb[(b * 8 + s) * 64 + l] = (unsigned short)f2bf(qa * 0.125f);
    }
  }
}

// ---------------------------------------------------------------------------
extern "C" void kernel_launch(void* const* d_in, const int* in_sizes, int n_in,
                              void* d_out, int out_size, void* d_ws, size_t ws_size,
                              hipStream_t stream) {
  const float* x       = (const float*)d_in[0];
  const float* noise   = (const float*)d_in[1];
  const float* mu      = (const float*)d_in[2];
  const float* lsig    = (const float*)d_in[3];
  const float* ln_in_g = (const float*)d_in[4];
  const float* ln_in_b = (const float*)d_in[5];
  const float* ln_sl_g = (const float*)d_in[6];
  const float* ln_sl_b = (const float*)d_in[7];
  const float* ln_ml_g = (const float*)d_in[8];
  const float* ln_ml_b = (const float*)d_in[9];
  const float* Wq      = (const float*)d_in[10];
  const float* Wk      = (const float*)d_in[11];
  const float* Wv      = (const float*)d_in[12];
  const float* W_ih    = (const float*)d_in[13];
  const float* W_hh    = (const float*)d_in[14];
  const float* b_ih    = (const float*)d_in[15];
  const float* b_hh    = (const float*)d_in[16];
  const float* W1      = (const float*)d_in[17];
  const float* b1      = (const float*)d_in[18];
  const float* W2      = (const float*)d_in[19];
  const float* b2      = (const float*)d_in[20];

  unsigned short* Xn  = (unsigned short*)d_ws;          // 32*16384*64 bf16
  unsigned short* XnT = Xn + (size_t)BB * NN * 64;      // 32*64*16384 bf16
  unsigned short* qkb = XnT + (size_t)BB * NN * 64;     // 256*64 bf16
  float* M     = (float*)(qkb + 16384);                 // 64*64
  float* Wihv  = M + 4096;                              // 192*64
  float* slots = Wihv + 12288;                          // 32*8*64
  float* Wpart = slots + 16384;                         // 1024*512
  float* cpart = Wpart + (size_t)1024 * 512;            // 1024*8

  prep_kernel<<<dim3(64), dim3(256), 0, stream>>>(Wq, Wk, W_ih, Wv, M, Wihv);
  init_qk_kernel<<<dim3(256), dim3(64), 0, stream>>>(
      noise, mu, lsig, slots, ln_sl_g, ln_sl_b, M, qkb);

  // iteration 1 fused into the LN pass (also materializes Xn + XnT)
  attn_kernel<0><<<dim3(1024), dim3(256), 0, stream>>>(
      x, nullptr, ln_in_g, ln_in_b, Xn, XnT, qkb, Wpart, cpart);

  for (int it = 0; it < 3; ++it) {
    update_kernel<<<dim3(256), dim3(256), 0, stream>>>(
        Wpart, cpart, slots, (it == 2) ? (float*)d_out : slots,
        Wihv, W_hh, b_ih, b_hh, ln_ml_g, ln_ml_b, W1, b1, W2, b2,
        ln_sl_g, ln_sl_b, M, qkb, (it < 2) ? 1 : 0);
    if (it < 2)
      attn_kernel<1><<<dim3(1024), dim3(256), 0, stream>>>(
          x, Xn, ln_in_g, ln_in_b, nullptr, XnT, qkb, Wpart, cpart);
  }
}

// Round 8
// 330.966 us; speedup vs baseline: 1.0341x; 1.0341x over previous
//
#include <hip/hip_runtime.h>

#define BB 32
#define NN 16384

typedef __attribute__((ext_vector_type(4))) float f4;
typedef __attribute__((ext_vector_type(8))) short short8;

__device__ __forceinline__ unsigned int f2bf(float f) {
  unsigned int u = __float_as_uint(f);
  return (u + 0x7fffu + ((u >> 16) & 1u)) >> 16;
}
__device__ __forceinline__ short bfs(float f) { return (short)f2bf(f); }

// ---------------------------------------------------------------------------
// prep: M = Wq^T @ Wk  (64x64);  Wihv = W_ih @ Wv  (192x64).
// ---------------------------------------------------------------------------
__global__ void __launch_bounds__(256) prep_kernel(
    const float* __restrict__ Wq, const float* __restrict__ Wk,
    const float* __restrict__ W_ih, const float* __restrict__ Wv,
    float* __restrict__ M, float* __restrict__ Wihv)
{
  int id = blockIdx.x * 256 + threadIdx.x;  // grid 64 -> 16384
  if (id < 4096) {
    int e1 = id >> 6, e2 = id & 63;
    float acc = 0.f;
    for (int d = 0; d < 64; ++d) acc += Wq[d * 64 + e1] * Wk[d * 64 + e2];
    M[id] = acc;
  } else {
    int t = (id - 4096) >> 6, e = id & 63;
    float acc = 0.f;
    for (int k = 0; k < 64; ++k) acc += W_ih[t * 64 + k] * Wv[k * 64 + e];
    Wihv[t * 64 + e] = acc;
  }
}

// ---------------------------------------------------------------------------
// init_qk: slots = mu + exp(lsig)*noise; qk = bf16(LN(slots) @ M * 0.125).
// ---------------------------------------------------------------------------
__global__ void __launch_bounds__(64) init_qk_kernel(
    const float* __restrict__ noise, const float* __restrict__ mu,
    const float* __restrict__ lsig, float* __restrict__ slots,
    const float* __restrict__ gs, const float* __restrict__ bsl,
    const float* __restrict__ M, unsigned short* __restrict__ qkb)
{
  const int bsi = blockIdx.x, l = threadIdx.x;
  const int idx = bsi * 64 + l;
  __shared__ float sh[64];
  float v = mu[idx & 511] + __expf(lsig[idx & 511]) * noise[idx];
  slots[idx] = v;
  float sm = v, sq = v * v;
#pragma unroll
  for (int m = 1; m < 64; m <<= 1) { sm += __shfl_xor(sm, m); sq += __shfl_xor(sq, m); }
  float mean = sm * (1.f / 64.f);
  float var = sq * (1.f / 64.f) - mean * mean;
  sh[l] = (v - mean) * rsqrtf(var + 1e-5f) * gs[l] + bsl[l];
  float acc = 0.f;
  for (int k = 0; k < 64; ++k) acc += sh[k] * M[k * 64 + l];
  qkb[idx] = (unsigned short)f2bf(acc * 0.125f);
}

// ---------------------------------------------------------------------------
// attn: MODE 0 = read x fp32, LN, write Xn bf16 + XnT2 (tiled transpose),
//                fused iter-1 attention (PV via LDS XT tiles it builds anyway).
//       MODE 1 = read Xn (logits) + XnT2 (PV B-frags direct) — no LDS transpose.
// grid 1024 (= 32 b x 32 ch, 512 rows/block), 256 thr = 4 waves x 32-row units.
// Logits (transposed form): lg = mfma(qkA, a) : D[s'=quad*4+r][n=l15];
//   slot-sum = in-lane add4 + xor16 + xor32, x0.5. Pt[s'][n] <- p.
// PV: pf = Pt[l15][quad*8..] (A-frag P^T), cv[t] = B[k=n_loc][col=e].
// XnT2 layout: [b][nt=n>>5][e=0..63][nl=n&31] — 4-KB tile per 32-row unit;
//   every wave instruction touches one contiguous 2-KB slab.
// ---------------------------------------------------------------------------
template <int MODE>
__global__ void __launch_bounds__(256) attn_kernel(
    const float* __restrict__ x, const unsigned short* __restrict__ Xin,
    const float* __restrict__ gin, const float* __restrict__ bin,
    unsigned short* __restrict__ Xout, unsigned short* __restrict__ XnT,
    const unsigned short* __restrict__ qkb,
    float* __restrict__ Wpart, float* __restrict__ cpart)
{
  constexpr int SMS = (MODE == 0) ? 16896 : 6720;
  __shared__ __align__(16) unsigned short SMEM[SMS];

  const int tid = threadIdx.x, wave = tid >> 6, lane = tid & 63;
  const int l15 = lane & 15, quad = lane >> 4;
  const int blk = blockIdx.x;
  const int b = blk >> 5;
  const int k0 = quad * 8;

  unsigned short* xt  = (MODE == 0) ? (SMEM + wave * 3584) : nullptr;
  unsigned short* Ptw = (MODE == 0) ? (SMEM + 14336 + wave * 640)
                                    : (SMEM + wave * 640);

  // qk fragments: per-lane qk[s=l15&7][e=k0+jj]; A[row=l15][k=e] (dup rows).
  const unsigned short* qrow = qkb + (((b << 3) + (l15 & 7)) << 6) + k0;
  const short8 qkA0 = *(const short8*)qrow;
  const short8 qkA1 = *(const short8*)(qrow + 32);

  f4 g0a, g0b, g1a, g1b, h0a, h0b, h1a, h1b;
  if constexpr (MODE == 0) {
    g0a = *(const f4*)(gin + k0);      g0b = *(const f4*)(gin + k0 + 4);
    g1a = *(const f4*)(gin + k0 + 32); g1b = *(const f4*)(gin + k0 + 36);
    h0a = *(const f4*)(bin + k0);      h0b = *(const f4*)(bin + k0 + 4);
    h1a = *(const f4*)(bin + k0 + 32); h1b = *(const f4*)(bin + k0 + 36);
  }

  const size_t row00 = (size_t)blk * 512 + wave * 32 + l15;  // unit0 half0 row
  // tile index of this wave's unit-0: nt0 = (blk&31)*16 + wave; unit u: +4u
  const int nt0 = ((blk & 31) << 4) + wave;

  f4 wacc[4];
#pragma unroll
  for (int t = 0; t < 4; ++t) wacc[t] = (f4){0.f, 0.f, 0.f, 0.f};
  float cac0 = 0.f, cac1 = 0.f, cac2 = 0.f, cac3 = 0.f;

  f4 cc[2][4];      // MODE 0 current unit (fp32)
  short8 aa[2][2];  // MODE 1 current unit (bf16)
  short8 cv[4];     // MODE 1 current unit PV B-frags
  // MODE1 per-lane base inside unit-0 tile: (t*16+l15)*32 + quad*8  (+t<<9)
  const unsigned short* vB =
      (MODE == 1) ? (XnT + ((((size_t)(b << 9)) + nt0) << 11) + (l15 << 5) + (quad << 3))
                  : nullptr;

  if constexpr (MODE == 0) {
    const float* xp = x + row00 * 64 + k0;
#pragma unroll
    for (int s = 0; s < 2; ++s) {
      const float* sp = xp + s * 1024;
      cc[s][0] = *(const f4*)sp;        cc[s][1] = *(const f4*)(sp + 4);
      cc[s][2] = *(const f4*)(sp + 32); cc[s][3] = *(const f4*)(sp + 36);
    }
  } else {
    const unsigned short* xb = Xin + row00 * 64 + k0;
#pragma unroll
    for (int s = 0; s < 2; ++s) {
      aa[s][0] = *(const short8*)(xb + s * 1024);
      aa[s][1] = *(const short8*)(xb + s * 1024 + 32);
    }
#pragma unroll
    for (int t = 0; t < 4; ++t)
      cv[t] = *(const short8*)(vB + (t << 9));
  }

#pragma unroll
  for (int u = 0; u < 4; ++u) {
    f4 nc[2][4];
    short8 na[2][2];
    short8 nv[4];
    if (u < 3) {  // prefetch next unit (128 rows ahead; next tile: +4 tiles)
      if constexpr (MODE == 0) {
        const float* xp = x + (row00 + (size_t)(u + 1) * 128) * 64 + k0;
#pragma unroll
        for (int s = 0; s < 2; ++s) {
          const float* sp = xp + s * 1024;
          nc[s][0] = *(const f4*)sp;        nc[s][1] = *(const f4*)(sp + 4);
          nc[s][2] = *(const f4*)(sp + 32); nc[s][3] = *(const f4*)(sp + 36);
        }
      } else {
        const unsigned short* xb = Xin + (row00 + (size_t)(u + 1) * 128) * 64 + k0;
#pragma unroll
        for (int s = 0; s < 2; ++s) {
          na[s][0] = *(const short8*)(xb + s * 1024);
          na[s][1] = *(const short8*)(xb + s * 1024 + 32);
        }
#pragma unroll
        for (int t = 0; t < 4; ++t)
          nv[t] = *(const short8*)(vB + (t << 9) + ((size_t)(u + 1) << 13));
      }
    }

#pragma unroll
    for (int s = 0; s < 2; ++s) {
      short8 a0, a1;
      if constexpr (MODE == 0) {
        float sm = 0.f, sq = 0.f;
#pragma unroll
        for (int j = 0; j < 4; ++j) {
          float v0 = cc[s][0][j], v1 = cc[s][1][j], v2 = cc[s][2][j], v3 = cc[s][3][j];
          sm += v0 + v1 + v2 + v3;
          sq += v0 * v0 + v1 * v1 + v2 * v2 + v3 * v3;
        }
        sm += __shfl_xor(sm, 16); sq += __shfl_xor(sq, 16);
        sm += __shfl_xor(sm, 32); sq += __shfl_xor(sq, 32);
        const float mean = sm * (1.f / 64.f);
        const float var = sq * (1.f / 64.f) - mean * mean;
        const float rstd = rsqrtf(var + 1e-5f);
#pragma unroll
        for (int j = 0; j < 4; ++j) {
          a0[j]     = bfs((cc[s][0][j] - mean) * rstd * g0a[j] + h0a[j]);
          a0[j + 4] = bfs((cc[s][1][j] - mean) * rstd * g0b[j] + h0b[j]);
          a1[j]     = bfs((cc[s][2][j] - mean) * rstd * g1a[j] + h1a[j]);
          a1[j + 4] = bfs((cc[s][3][j] - mean) * rstd * g1b[j] + h1b[j]);
        }
        unsigned short* xo = Xout + (row00 + (size_t)u * 128 + s * 16) * 64 + k0;
        *(short8*)xo = a0;
        *(short8*)(xo + 32) = a1;
        // scalar transposed stores: XT[e][n] at e*56 + ((e>>3)&3)*8 + n.
        const int nn = s * 16 + l15;
        unsigned short* xb0 = xt + (quad << 3) + nn;
#pragma unroll
        for (int jj = 0; jj < 8; ++jj) {
          xb0[(k0 + jj) * 56]      = (unsigned short)a0[jj];
          xb0[(k0 + jj + 32) * 56] = (unsigned short)a1[jj];
        }
      } else {
        a0 = aa[s][0]; a1 = aa[s][1];
      }

      // logits (transposed form): D[s'=quad*4+r][n=l15]; rows 8..15 dup 0..7
      f4 lg = (f4){0.f, 0.f, 0.f, 0.f};
      lg = __builtin_amdgcn_mfma_f32_16x16x32_bf16(qkA0, a0, lg, 0, 0, 0);
      lg = __builtin_amdgcn_mfma_f32_16x16x32_bf16(qkA1, a1, lg, 0, 0, 0);
      const float e0 = __expf(lg[0]), e1 = __expf(lg[1]);
      const float e2 = __expf(lg[2]), e3 = __expf(lg[3]);
      float ss = e0 + e1 + e2 + e3;
      ss += __shfl_xor(ss, 16);
      ss += __shfl_xor(ss, 32);         // sum over all 16 rows = 2x real sum
      const float rs = __builtin_amdgcn_rcpf(ss * 0.5f);
      const float p0 = e0 * rs, p1 = e1 * rs, p2 = e2 * rs, p3 = e3 * rs;
      cac0 += p0; cac1 += p1; cac2 += p2; cac3 += p3;
      unsigned short* pw = Ptw + (quad << 2) * 40 + s * 16 + l15;
      pw[0]   = (unsigned short)f2bf(p0);
      pw[40]  = (unsigned short)f2bf(p1);
      pw[80]  = (unsigned short)f2bf(p2);
      pw[120] = (unsigned short)f2bf(p3);
    }

    // P^T A-frag (same-wave DS ordering, proven pattern)
    short8 pf = *(const short8*)(Ptw + l15 * 40 + quad * 8);
#pragma unroll
    for (int t = 0; t < 4; ++t) {
      short8 cvv;
      if constexpr (MODE == 0) {
        const int rr = t * 16 + l15;
        cvv = *(const short8*)(xt + rr * 56 + (((rr >> 3) & 3) << 3) + (quad << 3));
      } else {
        cvv = cv[t];
      }
      wacc[t] = __builtin_amdgcn_mfma_f32_16x16x32_bf16(pf, cvv, wacc[t], 0, 0, 0);
    }

    if constexpr (MODE == 0) {
      // dump this unit's XT tile to XnT2 (fully contiguous: 2 KB per instr)
      unsigned short* tb = XnT + ((((size_t)(b << 9)) + nt0 + (u << 2)) << 11);
#pragma unroll
      for (int pass = 0; pass < 4; ++pass) {
        const int e = (pass << 4) + (lane >> 2);
        const int no = (lane & 3) << 3;
        const short8 vv =
            *(const short8*)(xt + e * 56 + (((e >> 3) & 3) << 3) + no);
        *(short8*)(tb + (pass << 9) + ((lane >> 2) << 5) + no) = vv;
      }
    }

    if (u < 3) {
      if constexpr (MODE == 0) {
#pragma unroll
        for (int s = 0; s < 2; ++s)
#pragma unroll
          for (int j = 0; j < 4; ++j) cc[s][j] = nc[s][j];
      } else {
#pragma unroll
        for (int s = 0; s < 2; ++s) { aa[s][0] = na[s][0]; aa[s][1] = na[s][1]; }
#pragma unroll
        for (int t = 0; t < 4; ++t) cv[t] = nv[t];
      }
    }
  }

  // epilogue: reduce cac over the 16 columns (n), stash per-wave partials.
#pragma unroll
  for (int m = 1; m < 16; m <<= 1) {
    cac0 += __shfl_xor(cac0, m); cac1 += __shfl_xor(cac1, m);
    cac2 += __shfl_xor(cac2, m); cac3 += __shfl_xor(cac3, m);
  }
  float* redw;
  float* credw;
  if constexpr (MODE == 0) {   // overlay each wave's own XT region
    redw  = (float*)(SMEM + wave * 3584);
    credw = (float*)(SMEM + wave * 3584 + 1024);
  } else {
    redw  = (float*)(SMEM + 2560) + wave * 512;
    credw = (float*)(SMEM + 6656) + wave * 8;
  }
  if (l15 == 0 && quad < 2) {
    credw[quad * 4 + 0] = cac0; credw[quad * 4 + 1] = cac1;
    credw[quad * 4 + 2] = cac2; credw[quad * 4 + 3] = cac3;
  }
  if (quad < 2) {  // D rows 8..15 are s-duplicates
#pragma unroll
    for (int t = 0; t < 4; ++t)
#pragma unroll
      for (int r = 0; r < 4; ++r)
        redw[(quad * 4 + r) * 64 + (t << 4) + l15] = wacc[t][r];
  }
  __syncthreads();
  for (int i = tid; i < 512; i += 256) {
    float acc = 0.f;
#pragma unroll
    for (int w = 0; w < 4; ++w) {
      const float* rw = (MODE == 0) ? (const float*)(SMEM + w * 3584)
                                    : (const float*)(SMEM + 2560) + w * 512;
      acc += rw[i];
    }
    Wpart[(size_t)blk * 512 + i] = acc;
  }
  if (tid < 8) {
    float acc = 0.f;
#pragma unroll
    for (int w = 0; w < 4; ++w) {
      const float* cw = (MODE == 0) ? (const float*)(SMEM + w * 3584 + 1024)
                                    : (const float*)(SMEM + 6656) + w * 8;
      acc += cw[tid];
    }
    cpart[blk * 8 + tid] = acc;
  }
}

// ---------------------------------------------------------------------------
// update: per (b,s). xmean -> gi via Wihv (= W_ih@Wv), GRU + LN + MLP + res;
// emits next qk (= LN(slots_new) @ M * 0.125) when make_q.
// ---------------------------------------------------------------------------
__global__ void __launch_bounds__(256) update_kernel(
    const float* __restrict__ Wpart, const float* __restrict__ cpart,
    const float* __restrict__ slots, float* __restrict__ out,
    const float* __restrict__ Wihv, const float* __restrict__ W_hh,
    const float* __restrict__ b_ih, const float* __restrict__ b_hh,
    const float* __restrict__ g_mlp, const float* __restrict__ b_mlp,
    const float* __restrict__ W1, const float* __restrict__ b1,
    const float* __restrict__ W2, const float* __restrict__ b2,
    const float* __restrict__ gs, const float* __restrict__ bsl,
    const float* __restrict__ M, unsigned short* __restrict__ qkb, int make_q)
{
  const int bs = blockIdx.x;
  const int b = bs >> 3, s = bs & 7;
  const int tid = threadIdx.x;
  const int l = tid & 63, cq = tid >> 6;
  __shared__ float wred[4][64];
  __shared__ float credS[4];
  __shared__ float u_sh[64], sp_sh[64], giA[192], ghA[192], uln_sh[64], h_sh[128];

  float wp = 0.f, cp2 = 0.f;
  for (int c = cq * 8; c < cq * 8 + 8; ++c) {
    wp += Wpart[(size_t)(((b << 5) + c) * 8 + s) * 64 + l];
    cp2 += cpart[((b << 5) + c) * 8 + s];
  }
  wred[cq][l] = wp;
  if (l == 0) credS[cq] = cp2;
  __syncthreads();

  float sp = 0.f;
  if (tid < 64) {
    const float cs = credS[0] + credS[1] + credS[2] + credS[3];
    const float u = (wred[0][l] + wred[1][l] + wred[2][l] + wred[3][l]) / cs;
    sp = slots[(b * 8 + s) * 64 + l];
    u_sh[l] = u; sp_sh[l] = sp;   // u_sh holds xmean (pre-Wv space)
  }
  __syncthreads();

  if (tid < 192) {
    float accI = b_ih[tid], accH = b_hh[tid];
    const float* wi = Wihv + tid * 64;
    const float* wh = W_hh + tid * 64;
    for (int k = 0; k < 64; ++k) { accI += u_sh[k] * wi[k]; accH += sp_sh[k] * wh[k]; }
    giA[tid] = accI; ghA[tid] = accH;
  }
  __syncthreads();

  float upd = 0.f;
  if (tid < 64) {
    const float rg = 1.f / (1.f + __expf(-(giA[l] + ghA[l])));
    const float zg = 1.f / (1.f + __expf(-(giA[64 + l] + ghA[64 + l])));
    const float ng = tanhf(giA[128 + l] + rg * ghA[128 + l]);
    upd = (1.f - zg) * ng + zg * sp;
    float sm = upd, sq = upd * upd;
#pragma unroll
    for (int m = 1; m < 64; m <<= 1) { sm += __shfl_xor(sm, m); sq += __shfl_xor(sq, m); }
    const float mean = sm * (1.f / 64.f);
    const float var = sq * (1.f / 64.f) - mean * mean;
    uln_sh[l] = (upd - mean) * rsqrtf(var + 1e-5f) * g_mlp[l] + b_mlp[l];
  }
  __syncthreads();

  if (tid < 128) {
    float acc = b1[tid];
    const float* w1 = W1 + tid * 64;
    for (int k = 0; k < 64; ++k) acc += uln_sh[k] * w1[k];
    h_sh[tid] = fmaxf(acc, 0.f);
  }
  __syncthreads();

  if (tid < 64) {
    float acc = b2[l];
    const float* w2 = W2 + l * 128;
    for (int k = 0; k < 128; ++k) acc += h_sh[k] * w2[k];
    const float sv = upd + acc;
    out[(b * 8 + s) * 64 + l] = sv;
    if (make_q) {
      float sm2 = sv, sq2 = sv * sv;
#pragma unroll
      for (int m = 1; m < 64; m <<= 1) { sm2 += __shfl_xor(sm2, m); sq2 += __shfl_xor(sq2, m); }
      const float mean2 = sm2 * (1.f / 64.f);
      const float var2 = sq2 * (1.f / 64.f) - mean2 * mean2;
      u_sh[l] = (sv - mean2) * rsqrtf(var2 + 1e-5f) * gs[l] + bsl[l];
      float qa = 0.f;
      for (int k = 0; k < 64; ++k) qa += u_sh[k] * M[k * 64 + l];
      qkb[(b * 8 + s) * 64 + l] = (unsigned short)f2bf(qa * 0.125f);
    }
  }
}

// ---------------------------------------------------------------------------
extern "C" void kernel_launch(void* const* d_in, const int* in_sizes, int n_in,
                              void* d_out, int out_size, void* d_ws, size_t ws_size,
                              hipStream_t stream) {
  const float* x       = (const float*)d_in[0];
  const float* noise   = (const float*)d_in[1];
  const float* mu      = (const float*)d_in[2];
  const float* lsig    = (const float*)d_in[3];
  const float* ln_in_g = (const float*)d_in[4];
  const float* ln_in_b = (const float*)d_in[5];
  const float* ln_sl_g = (const float*)d_in[6];
  const float* ln_sl_b = (const float*)d_in[7];
  const float* ln_ml_g = (const float*)d_in[8];
  const float* ln_ml_b = (const float*)d_in[9];
  const float* Wq      = (const float*)d_in[10];
  const float* Wk      = (const float*)d_in[11];
  const float* Wv      = (const float*)d_in[12];
  const float* W_ih    = (const float*)d_in[13];
  const float* W_hh    = (const float*)d_in[14];
  const float* b_ih    = (const float*)d_in[15];
  const float* b_hh    = (const float*)d_in[16];
  const float* W1      = (const float*)d_in[17];
  const float* b1      = (const float*)d_in[18];
  const float* W2      = (const float*)d_in[19];
  const float* b2      = (const float*)d_in[20];

  unsigned short* Xn  = (unsigned short*)d_ws;          // 32*16384*64 bf16
  unsigned short* XnT = Xn + (size_t)BB * NN * 64;      // 32*512*2048 bf16 tiles
  unsigned short* qkb = XnT + (size_t)BB * NN * 64;     // 256*64 bf16
  float* M     = (float*)(qkb + 16384);                 // 64*64
  float* Wihv  = M + 4096;                              // 192*64
  float* slots = Wihv + 12288;                          // 32*8*64
  float* Wpart = slots + 16384;                         // 1024*512
  float* cpart = Wpart + (size_t)1024 * 512;            // 1024*8

  prep_kernel<<<dim3(64), dim3(256), 0, stream>>>(Wq, Wk, W_ih, Wv, M, Wihv);
  init_qk_kernel<<<dim3(256), dim3(64), 0, stream>>>(
      noise, mu, lsig, slots, ln_sl_g, ln_sl_b, M, qkb);

  // iteration 1 fused into the LN pass (also materializes Xn + XnT2)
  attn_kernel<0><<<dim3(1024), dim3(256), 0, stream>>>(
      x, nullptr, ln_in_g, ln_in_b, Xn, XnT, qkb, Wpart, cpart);

  for (int it = 0; it < 3; ++it) {
    update_kernel<<<dim3(256), dim3(256), 0, stream>>>(
        Wpart, cpart, slots, (it == 2) ? (float*)d_out : slots,
        Wihv, W_hh, b_ih, b_hh, ln_ml_g, ln_ml_b, W1, b1, W2, b2,
        ln_sl_g, ln_sl_b, M, qkb, (it < 2) ? 1 : 0);
    if (it < 2)
      attn_kernel<1><<<dim3(1024), dim3(256), 0, stream>>>(
          x, Xn, ln_in_g, ln_in_b, nullptr, XnT, qkb, Wpart, cpart);
  }
}

// Round 9
// 298.521 us; speedup vs baseline: 1.1465x; 1.1087x over previous
//
#include <hip/hip_runtime.h>

#define BB 32
#define NN 16384

typedef __attribute__((ext_vector_type(4))) float f4;
typedef __attribute__((ext_vector_type(8))) short short8;

__device__ __forceinline__ unsigned int f2bf(float f) {
  unsigned int u = __float_as_uint(f);
  return (u + 0x7fffu + ((u >> 16) & 1u)) >> 16;
}
__device__ __forceinline__ short bfs(float f) { return (short)f2bf(f); }

// pack 4 floats -> 4 OCP e4m3 bytes (low 4 bytes of returned uint)
__device__ __forceinline__ unsigned int pk4_fp8(float a, float b, float c, float d) {
  int w = __builtin_amdgcn_cvt_pk_fp8_f32(a, b, 0, false);
  w = __builtin_amdgcn_cvt_pk_fp8_f32(c, d, w, true);
  return (unsigned int)w;
}

// ---------------------------------------------------------------------------
// prep: M = Wq^T @ Wk  (64x64);  Wihv = W_ih @ Wv  (192x64).
// ---------------------------------------------------------------------------
__global__ void __launch_bounds__(256) prep_kernel(
    const float* __restrict__ Wq, const float* __restrict__ Wk,
    const float* __restrict__ W_ih, const float* __restrict__ Wv,
    float* __restrict__ M, float* __restrict__ Wihv)
{
  int id = blockIdx.x * 256 + threadIdx.x;  // grid 64 -> 16384
  if (id < 4096) {
    int e1 = id >> 6, e2 = id & 63;
    float acc = 0.f;
    for (int d = 0; d < 64; ++d) acc += Wq[d * 64 + e1] * Wk[d * 64 + e2];
    M[id] = acc;
  } else {
    int t = (id - 4096) >> 6, e = id & 63;
    float acc = 0.f;
    for (int k = 0; k < 64; ++k) acc += W_ih[t * 64 + k] * Wv[k * 64 + e];
    Wihv[t * 64 + e] = acc;
  }
}

// ---------------------------------------------------------------------------
// init_qk: slots = mu + exp(lsig)*noise; qk16 = bf16(LN(slots) @ M * 0.125).
// (iter-1 consumer MODE0 is bf16)
// ---------------------------------------------------------------------------
__global__ void __launch_bounds__(64) init_qk_kernel(
    const float* __restrict__ noise, const float* __restrict__ mu,
    const float* __restrict__ lsig, float* __restrict__ slots,
    const float* __restrict__ gs, const float* __restrict__ bsl,
    const float* __restrict__ M, unsigned short* __restrict__ qkb16)
{
  const int bsi = blockIdx.x, l = threadIdx.x;
  const int idx = bsi * 64 + l;
  __shared__ float sh[64];
  float v = mu[idx & 511] + __expf(lsig[idx & 511]) * noise[idx];
  slots[idx] = v;
  float sm = v, sq = v * v;
#pragma unroll
  for (int m = 1; m < 64; m <<= 1) { sm += __shfl_xor(sm, m); sq += __shfl_xor(sq, m); }
  float mean = sm * (1.f / 64.f);
  float var = sq * (1.f / 64.f) - mean * mean;
  sh[l] = (v - mean) * rsqrtf(var + 1e-5f) * gs[l] + bsl[l];
  float acc = 0.f;
  for (int k = 0; k < 64; ++k) acc += sh[k] * M[k * 64 + l];
  qkb16[idx] = (unsigned short)f2bf(acc * 0.125f);
}

// ---------------------------------------------------------------------------
// attn: MODE 0 = read x fp32, LN, write Xn fp8 + XnT2 fp8 (tiled transpose),
//                fused iter-1 attention in bf16 (LDS XT bf16, qk bf16).
//       MODE 1 = read Xn fp8 (logits) + XnT2 fp8 (PV B-frags), fp8 MFMA.
// grid 1024 (= 32 b x 32 ch, 512 rows/block), 256 thr = 4 waves x 32-row units.
// Logits (transposed form): lg = mfma(qkA, a) : D[s'=quad*4+r][n=l15];
//   slot-sum = in-lane add4 + xor16 + xor32, x0.5. Pt[s'][n] <- p.
// PV: pf = Pt[l15][quad*8..] (A-frag P^T), cv[t] = B[k=n_loc][col=e].
// XnT2 fp8 layout: [b][nt=n>>5][e=0..63][nl=n&31] bytes — 2-KB tile/unit.
// fp8 16x16x32 fragment geometry == bf16 16x16x32 (8 elems/lane, k=quad*8+j).
// ---------------------------------------------------------------------------
template <int MODE>
__global__ void __launch_bounds__(256) attn_kernel(
    const float* __restrict__ x, const unsigned char* __restrict__ Xin,
    const float* __restrict__ gin, const float* __restrict__ bin,
    unsigned char* __restrict__ Xout, unsigned char* __restrict__ XnT,
    const unsigned short* __restrict__ qkb16, const unsigned char* __restrict__ qkb8,
    float* __restrict__ Wpart, float* __restrict__ cpart)
{
  constexpr int SMS = (MODE == 0) ? 16896 : 5440;  // shorts
  __shared__ __align__(16) unsigned short SMEM[SMS];

  const int tid = threadIdx.x, wave = tid >> 6, lane = tid & 63;
  const int l15 = lane & 15, quad = lane >> 4;
  const int blk = blockIdx.x;
  const int b = blk >> 5;
  const int k0 = quad * 8;  // element index

  unsigned short* xt  = (MODE == 0) ? (SMEM + wave * 3584) : nullptr;       // bf16 XT
  unsigned short* Pt16 = (MODE == 0) ? (SMEM + 14336 + wave * 640) : nullptr;
  unsigned char*  Pt8  = (MODE == 1) ? ((unsigned char*)SMEM + wave * 640) : nullptr;

  // qk fragments
  short8 qkA0_16, qkA1_16;
  unsigned long qkA0_8 = 0, qkA1_8 = 0;
  if constexpr (MODE == 0) {
    const unsigned short* qrow = qkb16 + (((b << 3) + (l15 & 7)) << 6) + k0;
    qkA0_16 = *(const short8*)qrow;
    qkA1_16 = *(const short8*)(qrow + 32);
  } else {
    const unsigned char* qrow = qkb8 + (((b << 3) + (l15 & 7)) << 6) + k0;
    qkA0_8 = *(const unsigned long*)qrow;
    qkA1_8 = *(const unsigned long*)(qrow + 32);
  }

  f4 g0a, g0b, g1a, g1b, h0a, h0b, h1a, h1b;
  if constexpr (MODE == 0) {
    g0a = *(const f4*)(gin + k0);      g0b = *(const f4*)(gin + k0 + 4);
    g1a = *(const f4*)(gin + k0 + 32); g1b = *(const f4*)(gin + k0 + 36);
    h0a = *(const f4*)(bin + k0);      h0b = *(const f4*)(bin + k0 + 4);
    h1a = *(const f4*)(bin + k0 + 32); h1b = *(const f4*)(bin + k0 + 36);
  }

  const size_t row00 = (size_t)blk * 512 + wave * 32 + l15;  // unit0 half0 row
  const int nt0 = ((blk & 31) << 4) + wave;                  // unit0 tile; +4/unit

  f4 wacc[4];
#pragma unroll
  for (int t = 0; t < 4; ++t) wacc[t] = (f4){0.f, 0.f, 0.f, 0.f};
  float cac0 = 0.f, cac1 = 0.f, cac2 = 0.f, cac3 = 0.f;

  f4 cc[2][4];                 // MODE 0 current unit (fp32)
  unsigned long a8[2][2];      // MODE 1 current unit (fp8: [s][chunk])
  unsigned long cv[4];         // MODE 1 current unit PV B-frags (fp8)
  const unsigned char* vB =
      (MODE == 1) ? (XnT + ((((size_t)(b << 9)) + nt0) << 11) + (l15 << 5) + (quad << 3))
                  : nullptr;

  if constexpr (MODE == 0) {
    const float* xp = x + row00 * 64 + k0;
#pragma unroll
    for (int s = 0; s < 2; ++s) {
      const float* sp = xp + s * 1024;
      cc[s][0] = *(const f4*)sp;        cc[s][1] = *(const f4*)(sp + 4);
      cc[s][2] = *(const f4*)(sp + 32); cc[s][3] = *(const f4*)(sp + 36);
    }
  } else {
    const unsigned char* xb = Xin + row00 * 64 + k0;
#pragma unroll
    for (int s = 0; s < 2; ++s) {
      a8[s][0] = *(const unsigned long*)(xb + s * 1024);
      a8[s][1] = *(const unsigned long*)(xb + s * 1024 + 32);
    }
#pragma unroll
    for (int t = 0; t < 4; ++t)
      cv[t] = *(const unsigned long*)(vB + (t << 9));
  }

#pragma unroll
  for (int u = 0; u < 4; ++u) {
    f4 nc[2][4];
    unsigned long na[2][2], nv[4];
    if (u < 3) {  // prefetch next unit (128 rows / +4 tiles ahead)
      if constexpr (MODE == 0) {
        const float* xp = x + (row00 + (size_t)(u + 1) * 128) * 64 + k0;
#pragma unroll
        for (int s = 0; s < 2; ++s) {
          const float* sp = xp + s * 1024;
          nc[s][0] = *(const f4*)sp;        nc[s][1] = *(const f4*)(sp + 4);
          nc[s][2] = *(const f4*)(sp + 32); nc[s][3] = *(const f4*)(sp + 36);
        }
      } else {
        const unsigned char* xb = Xin + (row00 + (size_t)(u + 1) * 128) * 64 + k0;
#pragma unroll
        for (int s = 0; s < 2; ++s) {
          na[s][0] = *(const unsigned long*)(xb + s * 1024);
          na[s][1] = *(const unsigned long*)(xb + s * 1024 + 32);
        }
#pragma unroll
        for (int t = 0; t < 4; ++t)
          nv[t] = *(const unsigned long*)(vB + (t << 9) + ((size_t)(u + 1) << 13));
      }
    }

#pragma unroll
    for (int s = 0; s < 2; ++s) {
      short8 a0_16, a1_16;          // MODE0 bf16 frags
      f4 lg = (f4){0.f, 0.f, 0.f, 0.f};
      if constexpr (MODE == 0) {
        float sm = 0.f, sq = 0.f;
#pragma unroll
        for (int j = 0; j < 4; ++j) {
          float v0 = cc[s][0][j], v1 = cc[s][1][j], v2 = cc[s][2][j], v3 = cc[s][3][j];
          sm += v0 + v1 + v2 + v3;
          sq += v0 * v0 + v1 * v1 + v2 * v2 + v3 * v3;
        }
        sm += __shfl_xor(sm, 16); sq += __shfl_xor(sq, 16);
        sm += __shfl_xor(sm, 32); sq += __shfl_xor(sq, 32);
        const float mean = sm * (1.f / 64.f);
        const float var = sq * (1.f / 64.f) - mean * mean;
        const float rstd = rsqrtf(var + 1e-5f);
        float f0[8], f1[8];
#pragma unroll
        for (int j = 0; j < 4; ++j) {
          f0[j]     = (cc[s][0][j] - mean) * rstd * g0a[j] + h0a[j];
          f0[j + 4] = (cc[s][1][j] - mean) * rstd * g0b[j] + h0b[j];
          f1[j]     = (cc[s][2][j] - mean) * rstd * g1a[j] + h1a[j];
          f1[j + 4] = (cc[s][3][j] - mean) * rstd * g1b[j] + h1b[j];
        }
#pragma unroll
        for (int j = 0; j < 8; ++j) { a0_16[j] = bfs(f0[j]); a1_16[j] = bfs(f1[j]); }
        // Xn fp8 store: 8B at e=k0.., 8B at e=k0+32..
        unsigned char* xo = Xout + (row00 + (size_t)u * 128 + s * 16) * 64 + k0;
        uint2 p0v2; p0v2.x = pk4_fp8(f0[0], f0[1], f0[2], f0[3]);
        p0v2.y = pk4_fp8(f0[4], f0[5], f0[6], f0[7]);
        *(uint2*)xo = p0v2;
        uint2 p1v2; p1v2.x = pk4_fp8(f1[0], f1[1], f1[2], f1[3]);
        p1v2.y = pk4_fp8(f1[4], f1[5], f1[6], f1[7]);
        *(uint2*)(xo + 32) = p1v2;
        // bf16 XT scalar transposed stores (proven path)
        const int nn = s * 16 + l15;
        unsigned short* xb0 = xt + (quad << 3) + nn;
#pragma unroll
        for (int jj = 0; jj < 8; ++jj) {
          xb0[(k0 + jj) * 56]      = (unsigned short)a0_16[jj];
          xb0[(k0 + jj + 32) * 56] = (unsigned short)a1_16[jj];
        }
        lg = __builtin_amdgcn_mfma_f32_16x16x32_bf16(qkA0_16, a0_16, lg, 0, 0, 0);
        lg = __builtin_amdgcn_mfma_f32_16x16x32_bf16(qkA1_16, a1_16, lg, 0, 0, 0);
      } else {
        lg = __builtin_amdgcn_mfma_f32_16x16x32_fp8_fp8(
            (long)qkA0_8, (long)a8[s][0], lg, 0, 0, 0);
        lg = __builtin_amdgcn_mfma_f32_16x16x32_fp8_fp8(
            (long)qkA1_8, (long)a8[s][1], lg, 0, 0, 0);
      }

      // softmax over 8 slots; D rows 8..15 duplicate 0..7
      const float e0 = __expf(lg[0]), e1 = __expf(lg[1]);
      const float e2 = __expf(lg[2]), e3 = __expf(lg[3]);
      float ss = e0 + e1 + e2 + e3;
      ss += __shfl_xor(ss, 16);
      ss += __shfl_xor(ss, 32);         // sum over all 16 rows = 2x real sum
      const float rs = __builtin_amdgcn_rcpf(ss * 0.5f);
      const float p0 = e0 * rs, p1 = e1 * rs, p2 = e2 * rs, p3 = e3 * rs;
      cac0 += p0; cac1 += p1; cac2 += p2; cac3 += p3;
      if constexpr (MODE == 0) {
        unsigned short* pw = Pt16 + (quad << 2) * 40 + s * 16 + l15;
        pw[0]   = (unsigned short)f2bf(p0);
        pw[40]  = (unsigned short)f2bf(p1);
        pw[80]  = (unsigned short)f2bf(p2);
        pw[120] = (unsigned short)f2bf(p3);
      } else {
        unsigned char* pw = Pt8 + (quad << 2) * 40 + s * 16 + l15;
        const unsigned int w1 = (unsigned int)__builtin_amdgcn_cvt_pk_fp8_f32(p0, p1, 0, false);
        const unsigned int w2 = (unsigned int)__builtin_amdgcn_cvt_pk_fp8_f32(p2, p3, 0, false);
        pw[0]   = (unsigned char)(w1 & 0xff);
        pw[40]  = (unsigned char)((w1 >> 8) & 0xff);
        pw[80]  = (unsigned char)(w2 & 0xff);
        pw[120] = (unsigned char)((w2 >> 8) & 0xff);
      }
    }

    // PV (same-wave DS ordering, proven pattern)
    if constexpr (MODE == 0) {
      short8 pf = *(const short8*)(Pt16 + l15 * 40 + quad * 8);
#pragma unroll
      for (int t = 0; t < 4; ++t) {
        const int rr = t * 16 + l15;
        const short8 cvv =
            *(const short8*)(xt + rr * 56 + (((rr >> 3) & 3) << 3) + (quad << 3));
        wacc[t] = __builtin_amdgcn_mfma_f32_16x16x32_bf16(pf, cvv, wacc[t], 0, 0, 0);
      }
      // dump this unit's XT tile to XnT2 as fp8 (contiguous 512B/instr)
      unsigned char* tb = XnT + ((((size_t)(b << 9)) + nt0 + (u << 2)) << 11);
#pragma unroll
      for (int pass = 0; pass < 4; ++pass) {
        const int e = (pass << 4) + (lane >> 2);
        const int no = (lane & 3) << 3;
        const short8 vv =
            *(const short8*)(xt + e * 56 + (((e >> 3) & 3) << 3) + no);
        float g[8];
#pragma unroll
        for (int j = 0; j < 8; ++j)
          g[j] = __uint_as_float(((unsigned int)(unsigned short)vv[j]) << 16);
        uint2 ov; ov.x = pk4_fp8(g[0], g[1], g[2], g[3]);
        ov.y = pk4_fp8(g[4], g[5], g[6], g[7]);
        *(uint2*)(tb + (e << 5) + no) = ov;
      }
    } else {
      const unsigned long pf = *(const unsigned long*)(Pt8 + l15 * 40 + quad * 8);
#pragma unroll
      for (int t = 0; t < 4; ++t)
        wacc[t] = __builtin_amdgcn_mfma_f32_16x16x32_fp8_fp8(
            (long)pf, (long)cv[t], wacc[t], 0, 0, 0);
    }

    if (u < 3) {
      if constexpr (MODE == 0) {
#pragma unroll
        for (int s = 0; s < 2; ++s)
#pragma unroll
          for (int j = 0; j < 4; ++j) cc[s][j] = nc[s][j];
      } else {
#pragma unroll
        for (int s = 0; s < 2; ++s) { a8[s][0] = na[s][0]; a8[s][1] = na[s][1]; }
#pragma unroll
        for (int t = 0; t < 4; ++t) cv[t] = nv[t];
      }
    }
  }

  // epilogue: reduce cac over the 16 columns (n), stash per-wave partials.
#pragma unroll
  for (int m = 1; m < 16; m <<= 1) {
    cac0 += __shfl_xor(cac0, m); cac1 += __shfl_xor(cac1, m);
    cac2 += __shfl_xor(cac2, m); cac3 += __shfl_xor(cac3, m);
  }
  float* redw;
  float* credw;
  if constexpr (MODE == 0) {   // overlay each wave's own XT region
    redw  = (float*)(SMEM + wave * 3584);
    credw = (float*)(SMEM + wave * 3584 + 1024);
  } else {
    redw  = (float*)(SMEM + 1280) + wave * 512;
    credw = (float*)(SMEM + 5376) + wave * 8;
  }
  if (l15 == 0 && quad < 2) {
    credw[quad * 4 + 0] = cac0; credw[quad * 4 + 1] = cac1;
    credw[quad * 4 + 2] = cac2; credw[quad * 4 + 3] = cac3;
  }
  if (quad < 2) {  // D rows 8..15 are s-duplicates
#pragma unroll
    for (int t = 0; t < 4; ++t)
#pragma unroll
      for (int r = 0; r < 4; ++r)
        redw[(quad * 4 + r) * 64 + (t << 4) + l15] = wacc[t][r];
  }
  __syncthreads();
  for (int i = tid; i < 512; i += 256) {
    float acc = 0.f;
#pragma unroll
    for (int w = 0; w < 4; ++w) {
      const float* rw = (MODE == 0) ? (const float*)(SMEM + w * 3584)
                                    : (const float*)(SMEM + 1280) + w * 512;
      acc += rw[i];
    }
    Wpart[(size_t)blk * 512 + i] = acc;
  }
  if (tid < 8) {
    float acc = 0.f;
#pragma unroll
    for (int w = 0; w < 4; ++w) {
      const float* cw = (MODE == 0) ? (const float*)(SMEM + w * 3584 + 1024)
                                    : (const float*)(SMEM + 5376) + w * 8;
      acc += cw[tid];
    }
    cpart[blk * 8 + tid] = acc;
  }
}

// ---------------------------------------------------------------------------
// update: per (b,s). xmean -> gi via Wihv (= W_ih@Wv), GRU + LN + MLP + res;
// emits next qk as fp8 (= LN(slots_new) @ M * 0.125) when make_q.
// ---------------------------------------------------------------------------
__global__ void __launch_bounds__(256) update_kernel(
    const float* __restrict__ Wpart, const float* __restrict__ cpart,
    const float* __restrict__ slots, float* __restrict__ out,
    const float* __restrict__ Wihv, const float* __restrict__ W_hh,
    const float* __restrict__ b_ih, const float* __restrict__ b_hh,
    const float* __restrict__ g_mlp, const float* __restrict__ b_mlp,
    const float* __restrict__ W1, const float* __restrict__ b1,
    const float* __restrict__ W2, const float* __restrict__ b2,
    const float* __restrict__ gs, const float* __restrict__ bsl,
    const float* __restrict__ M, unsigned char* __restrict__ qkb8, int make_q)
{
  const int bs = blockIdx.x;
  const int b = bs >> 3, s = bs & 7;
  const int tid = threadIdx.x;
  const int l = tid & 63, cq = tid >> 6;
  __shared__ float wred[4][64];
  __shared__ float credS[4];
  __shared__ float u_sh[64], sp_sh[64], giA[192], ghA[192], uln_sh[64], h_sh[128];

  float wp = 0.f, cp2 = 0.f;
  for (int c = cq * 8; c < cq * 8 + 8; ++c) {
    wp += Wpart[(size_t)(((b << 5) + c) * 8 + s) * 64 + l];
    cp2 += cpart[((b << 5) + c) * 8 + s];
  }
  wred[cq][l] = wp;
  if (l == 0) credS[cq] = cp2;
  __syncthreads();

  float sp = 0.f;
  if (tid < 64) {
    const float cs = credS[0] + credS[1] + credS[2] + credS[3];
    const float u = (wred[0][l] + wred[1][l] + wred[2][l] + wred[3][l]) / cs;
    sp = slots[(b * 8 + s) * 64 + l];
    u_sh[l] = u; sp_sh[l] = sp;   // u_sh holds xmean (pre-Wv space)
  }
  __syncthreads();

  if (tid < 192) {
    float accI = b_ih[tid], accH = b_hh[tid];
    const float* wi = Wihv + tid * 64;
    const float* wh = W_hh + tid * 64;
    for (int k = 0; k < 64; ++k) { accI += u_sh[k] * wi[k]; accH += sp_sh[k] * wh[k]; }
    giA[tid] = accI; ghA[tid] = accH;
  }
  __syncthreads();

  float upd = 0.f;
  if (tid < 64) {
    const float rg = 1.f / (1.f + __expf(-(giA[l] + ghA[l])));
    const float zg = 1.f / (1.f + __expf(-(giA[64 + l] + ghA[64 + l])));
    const float ng = tanhf(giA[128 + l] + rg * ghA[128 + l]);
    upd = (1.f - zg) * ng + zg * sp;
    float sm = upd, sq = upd * upd;
#pragma unroll
    for (int m = 1; m < 64; m <<= 1) { sm += __shfl_xor(sm, m); sq += __shfl_xor(sq, m); }
    const float mean = sm * (1.f / 64.f);
    const float var = sq * (1.f / 64.f) - mean * mean;
    uln_sh[l] = (upd - mean) * rsqrtf(var + 1e-5f) * g_mlp[l] + b_mlp[l];
  }
  __syncthreads();

  if (tid < 128) {
    float acc = b1[tid];
    const float* w1 = W1 + tid * 64;
    for (int k = 0; k < 64; ++k) acc += uln_sh[k] * w1[k];
    h_sh[tid] = fmaxf(acc, 0.f);
  }
  __syncthreads();

  if (tid < 64) {
    float acc = b2[l];
    const float* w2 = W2 + l * 128;
    for (int k = 0; k < 128; ++k) acc += h_sh[k] * w2[k];
    const float sv = upd + acc;
    out[(b * 8 + s) * 64 + l] = sv;
    if (make_q) {
      float sm2 = sv, sq2 = sv * sv;
#pragma unroll
      for (int m = 1; m < 64; m <<= 1) { sm2 += __shfl_xor(sm2, m); sq2 += __shfl_xor(sq2, m); }
      const float mean2 = sm2 * (1.f / 64.f);
      const float var2 = sq2 * (1.f / 64.f) - mean2 * mean2;
      u_sh[l] = (sv - mean2) * rsqrtf(var2 + 1e-5f) * gs[l] + bsl[l];
      float qa = 0.f;
      for (int k = 0; k < 64; ++k) qa += u_sh[k] * M[k * 64 + l];
      const unsigned int w =
          (unsigned int)__builtin_amdgcn_cvt_pk_fp8_f32(qa * 0.125f, 0.f, 0, false);
      qkb8[(b * 8 + s) * 64 + l] = (unsigned char)(w & 0xff);
    }
  }
}

// ---------------------------------------------------------------------------
extern "C" void kernel_launch(void* const* d_in, const int* in_sizes, int n_in,
                              void* d_out, int out_size, void* d_ws, size_t ws_size,
                              hipStream_t stream) {
  const float* x       = (const float*)d_in[0];
  const float* noise   = (const float*)d_in[1];
  const float* mu      = (const float*)d_in[2];
  const float* lsig    = (const float*)d_in[3];
  const float* ln_in_g = (const float*)d_in[4];
  const float* ln_in_b = (const float*)d_in[5];
  const float* ln_sl_g = (const float*)d_in[6];
  const float* ln_sl_b = (const float*)d_in[7];
  const float* ln_ml_g = (const float*)d_in[8];
  const float* ln_ml_b = (const float*)d_in[9];
  const float* Wq      = (const float*)d_in[10];
  const float* Wk      = (const float*)d_in[11];
  const float* Wv      = (const float*)d_in[12];
  const float* W_ih    = (const float*)d_in[13];
  const float* W_hh    = (const float*)d_in[14];
  const float* b_ih    = (const float*)d_in[15];
  const float* b_hh    = (const float*)d_in[16];
  const float* W1      = (const float*)d_in[17];
  const float* b1      = (const float*)d_in[18];
  const float* W2      = (const float*)d_in[19];
  const float* b2      = (const float*)d_in[20];

  unsigned char* Xn8   = (unsigned char*)d_ws;               // 32*16384*64 B
  unsigned char* XnT8  = Xn8 + (size_t)BB * NN * 64;         // 32*16384*64 B
  unsigned short* qk16 = (unsigned short*)(XnT8 + (size_t)BB * NN * 64);  // 16384
  unsigned char* qk8   = (unsigned char*)(qk16 + 16384);     // 16384 B
  float* M     = (float*)(qk8 + 16384);                      // 64*64
  float* Wihv  = M + 4096;                                   // 192*64
  float* slots = Wihv + 12288;                               // 32*8*64
  float* Wpart = slots + 16384;                              // 1024*512
  float* cpart = Wpart + (size_t)1024 * 512;                 // 1024*8

  prep_kernel<<<dim3(64), dim3(256), 0, stream>>>(Wq, Wk, W_ih, Wv, M, Wihv);
  init_qk_kernel<<<dim3(256), dim3(64), 0, stream>>>(
      noise, mu, lsig, slots, ln_sl_g, ln_sl_b, M, qk16);

  // iteration 1 fused into the LN pass (materializes Xn + XnT2, both fp8)
  attn_kernel<0><<<dim3(1024), dim3(256), 0, stream>>>(
      x, nullptr, ln_in_g, ln_in_b, Xn8, XnT8, qk16, nullptr, Wpart, cpart);

  for (int it = 0; it < 3; ++it) {
    update_kernel<<<dim3(256), dim3(256), 0, stream>>>(
        Wpart, cpart, slots, (it == 2) ? (float*)d_out : slots,
        Wihv, W_hh, b_ih, b_hh, ln_ml_g, ln_ml_b, W1, b1, W2, b2,
        ln_sl_g, ln_sl_b, M, qk8, (it < 2) ? 1 : 0);
    if (it < 2)
      attn_kernel<1><<<dim3(1024), dim3(256), 0, stream>>>(
          x, Xn8, ln_in_g, ln_in_b, nullptr, XnT8, nullptr, qk8, Wpart, cpart);
  }
}